// Round 10
// baseline (200.601 us; speedup 1.0000x reference)
//
#include <hip/hip_runtime.h>

// DPLSafePolicy: logits[16384,13] = x[16384,2048] @ [Wg|Wp|Wa], 3 softmaxes,
// sparse-T unsafe combine, renormalize -> out[16384,5].
//
// R10: LDS-staged x streaming. Cold-x read ran at ~2.5 TB/s in R1-R9; theory:
// 16384 concurrent row streams advancing in 128 B granules are HBM row-
// activate bound. Here each wave reads 1 KB CONTIGUOUS per instruction
// (64 lanes x 16 B), staging 32 rows x 1 KB chunks into dbuf LDS; MFMA
// A-frags then read from LDS. Register-staged pipeline: loads of chunk c+1
// issue before the barrier and stream while compute(c) runs; ds_writes at
// end of iter. Row pad +16 B -> (row + 2kg) mod 8 quad spread, 2-way = free.
// B-frags from L2-hot global, loaded before staging loads so vmcnt doesn't
// chain. Chunk order rotated per block. Epilogue unchanged from R9.

typedef __fp16 h2_t __attribute__((ext_vector_type(2)));
typedef __fp16 h4_t __attribute__((ext_vector_type(4)));
typedef __fp16 h8_t __attribute__((ext_vector_type(8)));
typedef float f32x4 __attribute__((ext_vector_type(4)));

#define ROWSTRIDE 260   // floats: 256 data + 4 pad

__global__ void pack_bfrag(const float* __restrict__ Wg,
                           const float* __restrict__ Wp,
                           const float* __restrict__ Wa,
                           h8_t* __restrict__ bfrag)
{
    const int t = blockIdx.x * 256 + threadIdx.x;   // 0..4095
    const int iter = t >> 6, lane = t & 63;
    const int n = lane & 15, kg = lane >> 4;
    h8_t v;
    #pragma unroll
    for (int j = 0; j < 8; ++j) {
        const int k = iter * 32 + kg * 8 + j;
        float f;
        if (n < 4)       f = Wg[k * 4 + n];
        else if (n < 8)  f = Wp[k * 4 + (n - 4)];
        else if (n < 13) f = Wa[k * 5 + (n - 8)];
        else             f = 0.f;
        v[j] = (__fp16)f;
    }
    bfrag[t] = v;
}

__global__ __launch_bounds__(256, 2)
void gemm_mfma(const float* __restrict__ x,
               const h8_t* __restrict__ bfrag,
               const float* __restrict__ bg, const float* __restrict__ bp,
               const float* __restrict__ ba, float* __restrict__ out)
{
    __shared__ float cbuf[2][32 * ROWSTRIDE];   // 2 x 33280 B
    __shared__ float dt[2][2][16][17];          // 8704 B

    const int tid = threadIdx.x;
    const int w   = tid >> 6;       // wave 0..3
    const int l   = tid & 63;
    const int rt2 = w & 1;          // MFMA row-tile within block
    const int ks  = w >> 1;         // K half within chunk (steps 0-3 / 4-7)
    const int row0 = blockIdx.x * 32;
    const int m  = l & 15;          // A row / D col
    const int kg = l >> 4;          // k-group

    const int cc0 = blockIdx.x & 7; // chunk-order rotation

    // staging: wave w owns rows w*8..w*8+7; lane l covers bytes l*16 of each
    const long srow = (long)(row0 + w * 8);
    f32x4 sr[8];

    // ---- prologue: stage chunk (loop idx 0) ----
    {
        const int cc = cc0;
        #pragma unroll
        for (int rr = 0; rr < 8; ++rr)
            sr[rr] = __builtin_nontemporal_load(
                (const f32x4*)(x + (srow + rr) * 2048 + cc * 256 + l * 4));
        #pragma unroll
        for (int rr = 0; rr < 8; ++rr)
            *(f32x4*)&cbuf[0][(w * 8 + rr) * ROWSTRIDE + l * 4] = sr[rr];
    }

    f32x4 acc = {0.f, 0.f, 0.f, 0.f};
    const int arow = (rt2 * 16 + m) * ROWSTRIDE;

    for (int c = 0; c < 8; ++c) {
        const int cc = (cc0 + c) & 7;

        // b-frags for THIS chunk first (their vmcnt wait won't chain on staging)
        h8_t b8[4];
        #pragma unroll
        for (int t = 0; t < 4; ++t)
            b8[t] = bfrag[(cc * 8 + ks * 4 + t) * 64 + l];

        // issue next chunk's streaming loads (1 KB contiguous per instr)
        const int ccn = (cc0 + c + 1) & 7;
        if (c + 1 < 8) {
            #pragma unroll
            for (int rr = 0; rr < 8; ++rr)
                sr[rr] = __builtin_nontemporal_load(
                    (const f32x4*)(x + (srow + rr) * 2048 + ccn * 256 + l * 4));
        }

        __syncthreads();   // chunk c committed to cbuf[c&1] by all waves

        const float* cb = cbuf[c & 1];
        #pragma unroll
        for (int t = 0; t < 4; ++t) {
            const int sl = ks * 4 + t;                 // step within chunk
            const int off = arow + sl * 32 + kg * 8;
            const f32x4 v0 = *(const f32x4*)&cb[off];
            const f32x4 v1 = *(const f32x4*)&cb[off + 4];
            const h2_t a01 = __builtin_amdgcn_cvt_pkrtz(v0.x, v0.y);
            const h2_t a23 = __builtin_amdgcn_cvt_pkrtz(v0.z, v0.w);
            const h2_t a45 = __builtin_amdgcn_cvt_pkrtz(v1.x, v1.y);
            const h2_t a67 = __builtin_amdgcn_cvt_pkrtz(v1.z, v1.w);
            const h4_t alo = __builtin_shufflevector(a01, a23, 0, 1, 2, 3);
            const h4_t ahi = __builtin_shufflevector(a45, a67, 0, 1, 2, 3);
            const h8_t a8  = __builtin_shufflevector(alo, ahi, 0, 1, 2, 3, 4, 5, 6, 7);
            acc = __builtin_amdgcn_mfma_f32_16x16x32_f16(a8, b8[t], acc, 0, 0, 0);
        }

        // commit next chunk to the other buffer (visible after next barrier)
        if (c + 1 < 8) {
            float* nb = cbuf[(c + 1) & 1];
            #pragma unroll
            for (int rr = 0; rr < 8; ++rr)
                *(f32x4*)&nb[(w * 8 + rr) * ROWSTRIDE + l * 4] = sr[rr];
        }
    }

    // D-frag: lane l, reg r -> D[row=kg*4+r][col=m]
    #pragma unroll
    for (int r = 0; r < 4; ++r)
        dt[rt2][ks][kg * 4 + r][m] = acc[r];
    __syncthreads();

    // epilogue: waves 0,1 (=row-tile), lanes 0..15 (=row within tile)
    if (w < 2 && l < 16) {
        float lg[13];
        #pragma unroll
        for (int c = 0; c < 13; ++c)
            lg[c] = dt[w][0][l][c] + dt[w][1][l][c];

        const float g0 = lg[0] + bg[0], g1 = lg[1] + bg[1], g2 = lg[2] + bg[2], g3 = lg[3] + bg[3];
        const float q0 = lg[4] + bp[0], q1 = lg[5] + bp[1], q2 = lg[6] + bp[2], q3 = lg[7] + bp[3];
        const float a0 = lg[8] + ba[0], a1 = lg[9] + ba[1], a2 = lg[10] + ba[2],
                    a3 = lg[11] + ba[3], a4 = lg[12] + ba[4];

        float mx, sum, inv;
        mx = fmaxf(fmaxf(g0, g1), fmaxf(g2, g3));
        const float eg0 = __expf(g0 - mx), eg1 = __expf(g1 - mx), eg2 = __expf(g2 - mx), eg3 = __expf(g3 - mx);
        sum = eg0 + eg1 + eg2 + eg3; inv = 1.f / sum;
        const float G0 = eg0 * inv, G1 = eg1 * inv, G2 = eg2 * inv, G3 = eg3 * inv;

        mx = fmaxf(fmaxf(q0, q1), fmaxf(q2, q3));
        const float ep0 = __expf(q0 - mx), ep1 = __expf(q1 - mx), ep2 = __expf(q2 - mx), ep3 = __expf(q3 - mx);
        sum = ep0 + ep1 + ep2 + ep3; inv = 1.f / sum;
        const float P0 = ep0 * inv, P1 = ep1 * inv, P2 = ep2 * inv, P3 = ep3 * inv;

        mx = fmaxf(fmaxf(fmaxf(a0, a1), fmaxf(a2, a3)), a4);
        const float ea0 = __expf(a0 - mx), ea1 = __expf(a1 - mx), ea2 = __expf(a2 - mx),
                    ea3 = __expf(a3 - mx), ea4 = __expf(a4 - mx);
        sum = ea0 + ea1 + ea2 + ea3 + ea4; inv = 1.f / sum;
        const float A0 = ea0 * inv, A1 = ea1 * inv, A2 = ea2 * inv, A3 = ea3 * inv, A4 = ea4 * inv;

        const float u0 = P0 * G0 + P1 * G1 + P2 * G2 + P3 * G3;  // stay
        const float u1 = P0 * G1 + P2 * G3;                      // up
        const float u2 = P1 * G0 + P3 * G2;                      // down

        const float j0 = A0 * (1.f - u0), j1 = A1 * (1.f - u1), j2 = A2 * (1.f - u2),
                    j3 = A3, j4 = A4;
        const float isd = 1.f / (j0 + j1 + j2 + j3 + j4);

        float* o = out + (long)(row0 + w * 16 + l) * 5;
        o[0] = j0 * isd; o[1] = j1 * isd; o[2] = j2 * isd; o[3] = j3 * isd; o[4] = j4 * isd;
    }
}

extern "C" void kernel_launch(void* const* d_in, const int* in_sizes, int n_in,
                              void* d_out, int out_size, void* d_ws, size_t ws_size,
                              hipStream_t stream) {
    const float* x  = (const float*)d_in[0];
    const float* Wg = (const float*)d_in[1];
    const float* bg = (const float*)d_in[2];
    const float* Wp = (const float*)d_in[3];
    const float* bp = (const float*)d_in[4];
    const float* Wa = (const float*)d_in[5];
    const float* ba = (const float*)d_in[6];
    float* out = (float*)d_out;

    h8_t* bfrag = (h8_t*)d_ws;   // 64 KB fragment table

    pack_bfrag<<<16, 256, 0, stream>>>(Wg, Wp, Wa, bfrag);
    gemm_mfma<<<512, 256, 0, stream>>>(x, bfrag, bg, bp, ba, out);
}